// Round 10
// baseline (133.078 us; speedup 1.0000x reference)
//
#include <hip/hip_runtime.h>
#include <hip/hip_bf16.h>

typedef __attribute__((ext_vector_type(8))) short short8;
typedef __attribute__((ext_vector_type(4))) float f32x4;
typedef unsigned short u16;
typedef unsigned int u32;

#define NROWS 8192
#define HALF  4096
#define DIM   256
#define TEMP_INV 2.0f   // 1/temperature
#define NBT 32                        // 8192/256 row strips
#define NBLK (NBT * (NBT + 1) / 2)    // 528 triangular tiles
#define NSLAB 160                     // 32 row-slots + 128 col-slots
#define PANELS 8                      // 256 cols / 32

#define BARRIER() asm volatile("s_barrier" ::: "memory")
#define WAITV(n)  asm volatile("s_waitcnt vmcnt(" #n ")" ::: "memory")

__device__ __forceinline__ u16 f2bf(float f) {
    union { float f; u32 i; } c; c.f = f;
    u32 lsb = (c.i >> 16) & 1;
    c.i += 0x7fffu + lsb;   // round-to-nearest-even
    return (u16)(c.i >> 16);
}

// ---------------- kernel 0: zero the slab ------------------------------------
__global__ __launch_bounds__(256) void zero_k(float4* __restrict__ p) {
    p[blockIdx.x * 256 + threadIdx.x] = float4{0.f, 0.f, 0.f, 0.f};
}

// ---------------- kernel 1: normalize rows, write bf16 ----------------------
__global__ __launch_bounds__(256) void normalize_k(const float* __restrict__ zi,
                                                   const float* __restrict__ zj,
                                                   u16* __restrict__ zn) {
    const int row  = blockIdx.x * 4 + (threadIdx.x >> 6);
    const int lane = threadIdx.x & 63;
    const float* src = (row < HALF) ? (zi + (size_t)row * DIM)
                                    : (zj + (size_t)(row - HALF) * DIM);
    float4 v = reinterpret_cast<const float4*>(src)[lane];
    float ss = v.x * v.x + v.y * v.y + v.z * v.z + v.w * v.w;
    #pragma unroll
    for (int m = 32; m; m >>= 1) ss += __shfl_xor(ss, m);
    const float inv = 1.0f / fmaxf(sqrtf(ss), 1e-8f);
    ushort4 o;
    o.x = f2bf(v.x * inv); o.y = f2bf(v.y * inv);
    o.z = f2bf(v.z * inv); o.w = f2bf(v.w * inv);
    reinterpret_cast<ushort4*>(zn + (size_t)row * DIM)[lane] = o;
}

// ---------------- kernel 2: A-in-regs panel-streaming triangular GEMM -------
// 4 waves x 64 rows; A (64 x 256 bf16) lives in 128 VGPR/lane, loaded ONCE.
// B streamed as 8 panels of 32 cols through 3 LDS bufs (48 KB), 1 barrier
// per panel, prefetch distance 2 panels. Output never materialized: exp +
// row/col sums accumulate in regs; unique slab slots (no atomics).
__device__ __forceinline__ void gload16(const void* g, void* lds) {
    __builtin_amdgcn_global_load_lds(
        (const __attribute__((address_space(1))) u32*)g,
        (__attribute__((address_space(3))) u32*)lds, 16, 0, 0);
}

__global__ __launch_bounds__(256, 2) void gemm_exp_rowsum(const u16* __restrict__ zn,
                                                          float* __restrict__ slab,
                                                          float* __restrict__ pos) {
    // XCD-aware bijective swizzle (528 = 8 * 66)
    const int b0 = blockIdx.x;
    const int b  = (b0 & 7) * (NBLK / 8) + (b0 >> 3);
    // Triangular decode: b -> (by, bx), by <= bx < 32
    int by = (int)((65.0f - sqrtf(65.0f * 65.0f - 8.0f * (float)b)) * 0.5f);
    while (by * (65 - by) / 2 > b) --by;
    while ((by + 1) * (64 - by) / 2 <= b) ++by;
    const int bx = by + (b - by * (65 - by) / 2);
    const bool diag  = (by == bx);
    const bool isPos = (bx - by == 16);

    const int rowBase = by * 256;
    const int colBase = bx * 256;

    __shared__ u16 BLds[3 * 8192];   // 3 bufs x 32 rows x 512 B = 48 KiB

    const int tid  = threadIdx.x;
    const int w    = tid >> 6;      // 0..3, wave owns rows [w*64, +64)
    const int lane = tid & 63;

    // ---- A panel -> registers (once). frag(mi,ks): row = w*64+mi*16+(lane&15),
    // bytes [ks*64 + (lane>>4)*16, +16)
    short8 ar[4][8];
    const u16* aBase = zn + (size_t)(rowBase + w * 64 + (lane & 15)) * DIM
                       + (lane >> 4) * 8;
    #pragma unroll
    for (int mi = 0; mi < 4; ++mi)
        #pragma unroll
        for (int ks = 0; ks < 8; ++ks)
            ar[mi][ks] = *reinterpret_cast<const short8*>(
                aBase + (size_t)mi * 16 * DIM + ks * 32);

    // ---- B panel staging: panel = 32 zn-rows x 512 B. Instr j of wave w fills
    // LDS 1KB block (w*4+j): lane l -> row (w*4+j)*2+(l>>5), chunk l&31.
    // Chunk-XOR swizzle (both sides): LDS chunk c holds global chunk c^(row&7).
    auto stageP = [&](int d, int p) {
        #pragma unroll
        for (int j = 0; j < 4; ++j) {
            const int row = (w * 4 + j) * 2 + (lane >> 5);
            const int g   = (lane & 31) ^ (row & 7);
            gload16(zn + (size_t)(colBase + p * 32 + row) * DIM + g * 8,
                    BLds + d * 8192 + (w * 4 + j) * 512);
        }
    };

    // ---- B frag read: global chunk G = ks*4 + (lane>>4) of row ni*16+(lane&15)
    auto rdB = [&](int d, int ni, int ks) -> short8 {
        const int row = ni * 16 + (lane & 15);
        const u32 off = (u32)(d * 16384 + row * 512
                              + (((ks * 4 + (lane >> 4)) ^ (row & 7)) << 4));
        return *reinterpret_cast<const short8*>(
            reinterpret_cast<const char*>(BLds) + off);
    };

    // prologue: A (32 loads) -> stage p0 -> stage p1 -> wait A+p0
    stageP(0, 0);
    stageP(1, 1);
    WAITV(4);   // in-order: A's 32 and p0's 4 retired; p1's 4 in flight
    BARRIER();

    float rs[4][4] = {};    // row sums, accumulated across panels
    float posv[4]  = {0.f, 0.f, 0.f, 0.f};

    #pragma unroll
    for (int p = 0; p < PANELS; ++p) {
        const int d = p % 3;
        if (p < 6) stageP((p + 2) % 3, p + 2);   // buf freed by last barrier

        f32x4 acc[4][2] = {};
        #pragma unroll
        for (int ks = 0; ks < 8; ++ks) {
            const short8 b0 = rdB(d, 0, ks);
            const short8 b1 = rdB(d, 1, ks);
            __builtin_amdgcn_s_setprio(1);
            #pragma unroll
            for (int mi = 0; mi < 4; ++mi) {
                acc[mi][0] = __builtin_amdgcn_mfma_f32_16x16x32_bf16(
                    ar[mi][ks], b0, acc[mi][0], 0, 0, 0);
                acc[mi][1] = __builtin_amdgcn_mfma_f32_16x16x32_bf16(
                    ar[mi][ks], b1, acc[mi][1], 0, 0, 0);
            }
            __builtin_amdgcn_s_setprio(0);
        }

        // ---- panel epilogue: exp + accumulate (no barriers needed)
        float cl0 = 0.f, cl1 = 0.f;
        #pragma unroll
        for (int mi = 0; mi < 4; ++mi)
            #pragma unroll
            for (int ni = 0; ni < 2; ++ni)
                #pragma unroll
                for (int v = 0; v < 4; ++v) {
                    const int R = w * 64 + mi * 16 + (lane >> 4) * 4 + v;
                    const int C = p * 32 + ni * 16 + (lane & 15);
                    const float val = acc[mi][ni][v];
                    if (isPos && R == C) posv[mi] = val;
                    float e = __expf(TEMP_INV * val);
                    if (diag && R == C) e = 0.f;   // exclude self-similarity
                    rs[mi][v] += e;
                    if (ni == 0) cl0 += e; else cl1 += e;
                }
        // col sums over the wave's 64 rows -> unique slot (zeros if diag to
        // keep vmcnt counts uniform; diag tile is fully covered by row sums)
        cl0 += __shfl_xor(cl0, 16); cl0 += __shfl_xor(cl0, 32);
        cl1 += __shfl_xor(cl1, 16); cl1 += __shfl_xor(cl1, 32);
        float* colSlot = slab + (size_t)(32 + by * 4 + w) * NROWS
                         + colBase + p * 32;
        if (lane < 16) {
            colSlot[lane]      = diag ? 0.f : cl0;
            colSlot[16 + lane] = diag ? 0.f : cl1;
        }

        // counted vmcnt: want stage(p+1) retired. Younger entries:
        // p=0: st(p+2)4 + sto(p)2 = 6; p=1..5: +sto(p-1)2 = 8; p=6: sto5+sto6=4
        if (p == 0)      { WAITV(6); BARRIER(); }
        else if (p < 6)  { WAITV(8); BARRIER(); }
        else if (p == 6) { WAITV(4); BARRIER(); }
    }

    // ---- block epilogue: row sums (reduce over 16 lanes = this wave's cols)
    float* rowSlot = slab + (size_t)bx * NROWS + rowBase + w * 64;
    #pragma unroll
    for (int mi = 0; mi < 4; ++mi) {
        f32x4 r;
        #pragma unroll
        for (int v = 0; v < 4; ++v) {
            float s = rs[mi][v];
            s += __shfl_xor(s, 1);
            s += __shfl_xor(s, 2);
            s += __shfl_xor(s, 4);
            s += __shfl_xor(s, 8);
            r[v] = s;
        }
        if ((lane & 15) == 0)
            *reinterpret_cast<f32x4*>(rowSlot + mi * 16 + (lane >> 4) * 4) = r;
    }
    // positives: tile diagonal of isPos blocks, captured pre-exp in posv
    if (isPos) {
        const int vq = (lane & 15) - (lane >> 4) * 4;
        if (vq >= 0 && vq < 4) {
            #pragma unroll
            for (int mi = 0; mi < 4; ++mi) {
                const int R = rowBase + w * 64 + mi * 16 + (lane & 15);
                pos[R] = posv[mi];
                pos[R + HALF] = posv[mi];
            }
        }
    }
}

// ---------------- kernel 3: reduce slab rows -> per-block partials ----------
__global__ __launch_bounds__(256) void finalize_k(const float* __restrict__ slab,
                                                  const float* __restrict__ pos,
                                                  float* __restrict__ part) {
    const int row = blockIdx.x * 256 + threadIdx.x;
    float d = 0.f;
    #pragma unroll 8
    for (int j = 0; j < NSLAB; ++j)
        d += slab[(size_t)j * NROWS + row];    // coalesced across threads
    float s = logf(d) - TEMP_INV * pos[row];
    __shared__ float red[256];
    red[threadIdx.x] = s;
    __syncthreads();
    #pragma unroll
    for (int m = 128; m; m >>= 1) {
        if (threadIdx.x < m) red[threadIdx.x] += red[threadIdx.x + m];
        __syncthreads();
    }
    if (threadIdx.x == 0) part[blockIdx.x] = red[0];
}

// ---------------- kernel 4: sum 32 partials (deterministic, no atomics) -----
__global__ __launch_bounds__(64) void sum_k(const float* __restrict__ part,
                                            float* __restrict__ out) {
    float v = (threadIdx.x < 32) ? part[threadIdx.x] : 0.f;
    #pragma unroll
    for (int m = 32; m; m >>= 1) v += __shfl_xor(v, m);
    if (threadIdx.x == 0) out[0] = v * (1.0f / NROWS);
}

extern "C" void kernel_launch(void* const* d_in, const int* in_sizes, int n_in,
                              void* d_out, int out_size, void* d_ws, size_t ws_size,
                              hipStream_t stream) {
    const float* zi = (const float*)d_in[0];
    const float* zj = (const float*)d_in[1];
    float* out = (float*)d_out;

    // workspace: zn bf16 [8192][256] (4 MiB) | slab f32 [160][8192] (5 MiB)
    //            | pos f32 [8192] | part f32 [32]
    u16*   zn   = (u16*)d_ws;
    float* slab = (float*)((char*)d_ws + (size_t)NROWS * DIM * sizeof(u16));
    float* pos  = slab + (size_t)NSLAB * NROWS;
    float* part = pos + NROWS;

    zero_k<<<(NSLAB * NROWS) / (256 * 4), 256, 0, stream>>>((float4*)slab);
    normalize_k<<<NROWS / 4, 256, 0, stream>>>(zi, zj, zn);
    gemm_exp_rowsum<<<NBLK, 256, 0, stream>>>(zn, slab, pos);
    finalize_k<<<NROWS / 256, 256, 0, stream>>>(slab, pos, part);
    sum_k<<<1, 64, 0, stream>>>(part, out);
}

// Round 11
// 54.555 us; speedup vs baseline: 2.4393x; 2.4393x over previous
//
#include <hip/hip_runtime.h>

typedef __attribute__((ext_vector_type(4))) float f32x4;
typedef unsigned int u32;
typedef long i64;

#define NROWS 8192
#define HALF  4096
#define DIM   256
#define TEMP_INV 2.0f                 // 1/temperature
#define NBT 64                        // 8192/128 tiles per side
#define NBLK (NBT * (NBT + 1) / 2)    // 2080 triangular tiles
#define NSLAB 128                     // 64 row-slots + 64 col-slots

#define BARRIER() asm volatile("s_barrier" ::: "memory")
#define WAITV(n)  asm volatile("s_waitcnt vmcnt(" #n ")" ::: "memory")

// ---------------- kernel 0: zero the slab ------------------------------------
__global__ __launch_bounds__(256) void zero_k(float4* __restrict__ p) {
    p[blockIdx.x * 256 + threadIdx.x] = float4{0.f, 0.f, 0.f, 0.f};
}

// ---------------- kernel 1: normalize rows, write fp8 e4m3 ------------------
__global__ __launch_bounds__(256) void normalize_k(const float* __restrict__ zi,
                                                   const float* __restrict__ zj,
                                                   u32* __restrict__ zn8) {
    const int row  = blockIdx.x * 4 + (threadIdx.x >> 6);
    const int lane = threadIdx.x & 63;
    const float* src = (row < HALF) ? (zi + (size_t)row * DIM)
                                    : (zj + (size_t)(row - HALF) * DIM);
    float4 v = reinterpret_cast<const float4*>(src)[lane];
    float ss = v.x * v.x + v.y * v.y + v.z * v.z + v.w * v.w;
    #pragma unroll
    for (int m = 32; m; m >>= 1) ss += __shfl_xor(ss, m);
    const float inv = 1.0f / fmaxf(sqrtf(ss), 1e-8f);
    // pack 4 normalized values into 4 fp8 e4m3 bytes (RNE hardware convert)
    u32 pk = __builtin_amdgcn_cvt_pk_fp8_f32(v.x * inv, v.y * inv, 0, false);
    pk     = __builtin_amdgcn_cvt_pk_fp8_f32(v.z * inv, v.w * inv, pk, true);
    zn8[(size_t)row * (DIM / 4) + lane] = pk;
}

// ---------------- kernel 2: fp8 A-in-regs panel-streaming triangular GEMM ---
// 128^2 tiles, 4 waves x 32 rows. A (32x256 fp8) = 32 VGPR/lane, loaded once.
// B: 4 panels of 32 cols (8 KB) through 3 LDS bufs, 1 barrier/panel, prefetch
// distance 2, counted vmcnt. 16B-granular XOR swizzle (gload16-compatible).
// Row/col sums accumulate in regs; no stores inside the pipelined loop.
__device__ __forceinline__ void gload16(const void* g, void* lds) {
    __builtin_amdgcn_global_load_lds(
        (const __attribute__((address_space(1))) u32*)g,
        (__attribute__((address_space(3))) u32*)lds, 16, 0, 0);
}

__global__ __launch_bounds__(256, 3) void gemm_exp_rowsum(
        const unsigned char* __restrict__ zn8,
        float* __restrict__ slab, float* __restrict__ pos) {
    // XCD-aware bijective swizzle (2080 = 8 * 260)
    const int b0 = blockIdx.x;
    const int b  = (b0 & 7) * (NBLK / 8) + (b0 >> 3);
    // Triangular decode: b -> (by, bx), by <= bx < 64
    int by = (int)((129.0f - sqrtf(129.0f * 129.0f - 8.0f * (float)b)) * 0.5f);
    while (by * (129 - by) / 2 > b) --by;
    while ((by + 1) * (129 - (by + 1)) / 2 <= b) ++by;
    const int bx = by + (b - by * (129 - by) / 2);
    const bool diag  = (by == bx);
    const bool isPos = (bx - by == 32);

    const int rowBase = by * 128;
    const int colBase = bx * 128;

    __shared__ char LDSB[3 * 8192];   // 3 panel bufs; reused for col-reduce

    const int tid  = threadIdx.x;
    const int w    = tid >> 6;      // 0..3, wave owns rows [w*32, +32)
    const int lane = tid & 63;

    // ---- A -> registers (once): frag(mi,ks) = 8 fp8, row w*32+mi*16+(lane&15),
    // k in [ks*32 + (lane>>4)*8, +8)
    i64 ar[2][8];
    const unsigned char* aBase = zn8 + (size_t)(rowBase + w * 32 + (lane & 15)) * DIM
                                 + (lane >> 4) * 8;
    #pragma unroll
    for (int mi = 0; mi < 2; ++mi)
        #pragma unroll
        for (int ks = 0; ks < 8; ++ks)
            ar[mi][ks] = *reinterpret_cast<const i64*>(
                aBase + (size_t)mi * 16 * DIM + ks * 32);

    // ---- B panel staging: panel = 32 zn-rows x 256 B. Wave w instr j covers
    // rows (w*2+j)*4 + (lane>>4); 16B unit q' = lane&15 holds global unit
    // q' ^ (row&7)  (16B-granular swizzle, both sides).
    auto stageP = [&](int d, int p) {
        #pragma unroll
        for (int j = 0; j < 2; ++j) {
            const int r  = (w * 2 + j) * 4 + (lane >> 4);
            const int gq = (lane & 15) ^ (r & 7);
            gload16(zn8 + (size_t)(colBase + p * 32 + r) * DIM + gq * 16,
                    LDSB + d * 8192 + (w * 2 + j) * 1024);
        }
    };

    // ---- B frag read (b64): row = ni*16+(lane&15) (row&7 == lane&7 for both
    // ni), global 16B unit q = ks*2 + ((lane>>4)>>1), half = (lane>>4)&1.
    const int k8    = lane & 7;
    const int hq    = (lane >> 4) >> 1;
    const int rowB  = (lane & 15) * 256 + ((lane >> 4) & 1) * 8;
    auto rdB = [&](int d, int ni, int ks) -> i64 {
        const int off = d * 8192 + ni * 4096 + rowB + (((ks * 2 + hq) ^ k8) << 4);
        return *reinterpret_cast<const i64*>(LDSB + off);
    };

    float rs[2][4] = {};
    float cs[8]    = {};
    float posv[2]  = {0.f, 0.f};

    stageP(0, 0);
    stageP(1, 1);
    WAITV(2);   // A (in-order, older) + panel0 retired; panel1's 2 in flight
    BARRIER();

    #pragma unroll
    for (int p = 0; p < 4; ++p) {
        const int d = p % 3;
        if (p < 2) stageP((p + 2) % 3, p + 2);   // buf freed by last barrier

        f32x4 acc[2][2] = {};
        #pragma unroll
        for (int ks = 0; ks < 8; ++ks) {
            const i64 b0v = rdB(d, 0, ks);
            const i64 b1v = rdB(d, 1, ks);
            __builtin_amdgcn_s_setprio(1);
            #pragma unroll
            for (int mi = 0; mi < 2; ++mi) {
                acc[mi][0] = __builtin_amdgcn_mfma_f32_16x16x32_fp8_fp8(
                    ar[mi][ks], b0v, acc[mi][0], 0, 0, 0);
                acc[mi][1] = __builtin_amdgcn_mfma_f32_16x16x32_fp8_fp8(
                    ar[mi][ks], b1v, acc[mi][1], 0, 0, 0);
            }
            __builtin_amdgcn_s_setprio(0);
        }

        // panel epilogue in regs only (C/D: col=lane&15, row=(lane>>4)*4+v)
        #pragma unroll
        for (int mi = 0; mi < 2; ++mi)
            #pragma unroll
            for (int ni = 0; ni < 2; ++ni)
                #pragma unroll
                for (int v = 0; v < 4; ++v) {
                    const int R = w * 32 + mi * 16 + (lane >> 4) * 4 + v;
                    const int C = p * 32 + ni * 16 + (lane & 15);
                    const float val = acc[mi][ni][v];
                    if (isPos && R == C) posv[mi] = val;
                    float e = __expf(TEMP_INV * val);
                    if (diag && R == C) e = 0.f;   // exclude self-similarity
                    rs[mi][v] += e;
                    cs[p * 2 + ni] += e;
                }

        if (p == 0)      { WAITV(2); BARRIER(); }   // panel1 ready; st2 flies
        else if (p == 1) { WAITV(2); BARRIER(); }   // panel2 ready; st3 flies
        else if (p == 2) { WAITV(0); BARRIER(); }   // panel3 ready
    }

    // ---- row sums: reduce across 16 col-lanes, coalesced f32x4 store
    float* rowSlot = slab + (size_t)bx * NROWS + rowBase + w * 32;
    #pragma unroll
    for (int mi = 0; mi < 2; ++mi) {
        f32x4 r;
        #pragma unroll
        for (int v = 0; v < 4; ++v) {
            float s = rs[mi][v];
            s += __shfl_xor(s, 1);
            s += __shfl_xor(s, 2);
            s += __shfl_xor(s, 4);
            s += __shfl_xor(s, 8);
            r[v] = s;
        }
        if ((lane & 15) == 0)
            *reinterpret_cast<f32x4*>(rowSlot + mi * 16 + (lane >> 4) * 4) = r;
    }

    // ---- col sums: per-wave reduce, then cross-wave via reused LDS
    __syncthreads();                    // panel reads done; LDSB reusable
    float* colred = reinterpret_cast<float*>(LDSB);
    #pragma unroll
    for (int g = 0; g < 8; ++g) {       // col = g*16 + (lane&15)
        float c = cs[g];
        c += __shfl_xor(c, 16);
        c += __shfl_xor(c, 32);
        if (lane < 16) colred[w * 128 + g * 16 + lane] = c;
    }
    __syncthreads();
    if (!diag && tid < 128) {
        const float sum = colred[tid] + colred[128 + tid]
                        + colred[256 + tid] + colred[384 + tid];
        slab[(size_t)(64 + by) * NROWS + colBase + tid] = sum;
    }

    // ---- positives: tile diagonal of isPos blocks (captured pre-exp)
    if (isPos) {
        const int vq = (lane & 15) - (lane >> 4) * 4;
        if (vq >= 0 && vq < 4) {
            #pragma unroll
            for (int mi = 0; mi < 2; ++mi) {
                const int Rg = rowBase + w * 32 + mi * 16 + (lane & 15);
                pos[Rg] = posv[mi];
                pos[Rg + HALF] = posv[mi];
            }
        }
    }
}

// ---------------- kernel 3: reduce slab rows -> per-block partials ----------
__global__ __launch_bounds__(256) void finalize_k(const float* __restrict__ slab,
                                                  const float* __restrict__ pos,
                                                  float* __restrict__ part) {
    const int row = blockIdx.x * 256 + threadIdx.x;
    float d = 0.f;
    #pragma unroll 8
    for (int j = 0; j < NSLAB; ++j)
        d += slab[(size_t)j * NROWS + row];    // coalesced across threads
    float s = logf(d) - TEMP_INV * pos[row];
    __shared__ float red[256];
    red[threadIdx.x] = s;
    __syncthreads();
    #pragma unroll
    for (int m = 128; m; m >>= 1) {
        if (threadIdx.x < m) red[threadIdx.x] += red[threadIdx.x + m];
        __syncthreads();
    }
    if (threadIdx.x == 0) part[blockIdx.x] = red[0];
}

// ---------------- kernel 4: sum 32 partials (deterministic, no atomics) -----
__global__ __launch_bounds__(64) void sum_k(const float* __restrict__ part,
                                            float* __restrict__ out) {
    float v = (threadIdx.x < 32) ? part[threadIdx.x] : 0.f;
    #pragma unroll
    for (int m = 32; m; m >>= 1) v += __shfl_xor(v, m);
    if (threadIdx.x == 0) out[0] = v * (1.0f / NROWS);
}

extern "C" void kernel_launch(void* const* d_in, const int* in_sizes, int n_in,
                              void* d_out, int out_size, void* d_ws, size_t ws_size,
                              hipStream_t stream) {
    const float* zi = (const float*)d_in[0];
    const float* zj = (const float*)d_in[1];
    float* out = (float*)d_out;

    // workspace: zn8 fp8 [8192][256] (2 MiB) | slab f32 [128][8192] (4 MiB)
    //            | pos f32 [8192] | part f32 [32]
    unsigned char* zn8 = (unsigned char*)d_ws;
    float* slab = (float*)((char*)d_ws + (size_t)NROWS * DIM);
    float* pos  = slab + (size_t)NSLAB * NROWS;
    float* part = pos + NROWS;

    zero_k<<<(NSLAB * NROWS) / (256 * 4), 256, 0, stream>>>((float4*)slab);
    normalize_k<<<NROWS / 4, 256, 0, stream>>>(zi, zj, (u32*)zn8);
    gemm_exp_rowsum<<<NBLK, 256, 0, stream>>>(zn8, slab, pos);
    finalize_k<<<NROWS / 256, 256, 0, stream>>>(slab, pos, part);
    sum_k<<<1, 64, 0, stream>>>(part, out);
}